// Round 1
// 1489.439 us; speedup vs baseline: 1.0866x; 1.0866x over previous
//
#include <hip/hip_runtime.h>
#include <hip/hip_bf16.h>
#include <stdint.h>

#define NCELL 40000
#define EUE   200000
#define EDE   200000
#define EBE   120000
#define NM    ((size_t)NCELL * 256)

typedef __attribute__((ext_vector_type(8))) short bf16x8;
typedef __attribute__((ext_vector_type(4))) float f32x4;

__device__ __forceinline__ uint16_t f2bf(float f) {
  union { float f; uint32_t u; } v; v.f = f;
  uint32_t u = v.u;
  u += 0x7fffu + ((u >> 16) & 1u);   // round-to-nearest-even
  return (uint16_t)(u >> 16);
}

// ---------------- weight transpose + fp32->bf16 convert ----------------
struct WArgs {
  const float* src[11];
  uint16_t*    dst[11];
  int          K[11];
};

__global__ void k_wconv(WArgs a) {
  int m = blockIdx.z;
  int K = a.K[m];
  int k0 = blockIdx.x * 32;
  if (k0 >= K) return;
  int n0 = blockIdx.y * 32;
  __shared__ float t[32][33];
  int tx = threadIdx.x, ty = threadIdx.y;
  const float* src = a.src[m];
  for (int i = ty; i < 32; i += 8)
    t[i][tx] = src[(size_t)(k0 + i) * 256 + n0 + tx];
  __syncthreads();
  uint16_t* dst = a.dst[m];
  for (int i = ty; i < 32; i += 8)
    dst[(size_t)(n0 + i) * K + k0 + tx] = f2bf(t[tx][i]);
}

// ---------------- CSR build: count -> scan -> fill ----------------
__global__ void k_count(const int* __restrict__ tgt, int* __restrict__ cnt, int E) {
  int i = blockIdx.x * 256 + threadIdx.x;
  if (i < E) atomicAdd(&cnt[tgt[i]], 1);
}

struct ScanArgs { const int* cnt[3]; int* offs[3]; int* head[3]; };

__global__ void k_scan(ScanArgs a) {
  int s = blockIdx.x;
  const int n = NCELL;
  const int* cnt = a.cnt[s];
  int* offs = a.offs[s];
  int* head = a.head[s];
  __shared__ int buf[1024];
  __shared__ int carry;
  int tid = threadIdx.x;
  if (tid == 0) carry = 0;
  __syncthreads();
  for (int base = 0; base < n; base += 1024) {
    int i = base + tid;
    int v = (i < n) ? cnt[i] : 0;
    buf[tid] = v;
    __syncthreads();
    for (int d = 1; d < 1024; d <<= 1) {
      int t = (tid >= d) ? buf[tid - d] : 0;
      __syncthreads();
      buf[tid] += t;
      __syncthreads();
    }
    int excl = carry + buf[tid] - v;
    if (i < n) { offs[i] = excl; head[i] = excl; }
    __syncthreads();
    if (tid == 1023) carry += buf[1023];
    __syncthreads();
  }
  if (tid == 0) offs[n] = carry;
}

__global__ void k_fill(const int* __restrict__ src, const int* __restrict__ tgt,
                       int* __restrict__ head, int* __restrict__ perm,
                       int* __restrict__ psrc, int E) {
  int e = blockIdx.x * 256 + threadIdx.x;
  if (e < E) {
    int p = atomicAdd(&head[tgt[e]], 1);
    perm[p] = e;
    psrc[p] = src[e];
  }
}

// ---------------- segment sum (MSG in EDGE order, gathered via perm) ----------------
// out[t] = (1+eps)*x[t] + sum_{j in [offs[t],offs[t+1])} MSG[perm[j]]
__global__ void k_segsum(const float* __restrict__ MSG, const int* __restrict__ offs,
                         const int* __restrict__ perm, const float* __restrict__ x,
                         const float* __restrict__ eps, float* __restrict__ out) {
  int t = blockIdx.x * 4 + threadIdx.y;
  int c = threadIdx.x * 4;
  int s = offs[t], e = offs[t + 1];
  float sE = 1.f + *eps;
  float4 xa = *(const float4*)(x + (size_t)t * 256 + c);
  float a0 = xa.x * sE, a1 = xa.y * sE, a2 = xa.z * sE, a3 = xa.w * sE;
  int j = s;
  for (; j + 1 < e; j += 2) {
    int r0 = perm[j], r1 = perm[j + 1];
    float4 v0 = *(const float4*)(MSG + (size_t)r0 * 256 + c);
    float4 v1 = *(const float4*)(MSG + (size_t)r1 * 256 + c);
    a0 += v0.x + v1.x; a1 += v0.y + v1.y; a2 += v0.z + v1.z; a3 += v0.w + v1.w;
  }
  if (j < e) {
    int r0 = perm[j];
    float4 v0 = *(const float4*)(MSG + (size_t)r0 * 256 + c);
    a0 += v0.x; a1 += v0.y; a2 += v0.z; a3 += v0.w;
  }
  *(float4*)(out + (size_t)t * 256 + c) = make_float4(a0, a1, a2, a3);
}

// ---------------- boundary gather: out[t] = (1+eps)*x[t] + sum battr[psrc[j]] ----------------
__global__ void k_bgather(const float* __restrict__ battr, const int* __restrict__ offs,
                          const int* __restrict__ psrc, const float* __restrict__ x,
                          const float* __restrict__ eps, float* __restrict__ out) {
  int t = blockIdx.x * 4 + threadIdx.y;
  int c = threadIdx.x * 4;
  int s = offs[t], e = offs[t + 1];
  float sE = 1.f + *eps;
  float4 xa = *(const float4*)(x + (size_t)t * 256 + c);
  float a0 = xa.x * sE, a1 = xa.y * sE, a2 = xa.z * sE, a3 = xa.w * sE;
  int j = s;
  for (; j + 1 < e; j += 2) {
    int r0 = psrc[j], r1 = psrc[j + 1];
    float4 v0 = *(const float4*)(battr + (size_t)r0 * 256 + c);
    float4 v1 = *(const float4*)(battr + (size_t)r1 * 256 + c);
    a0 += v0.x + v1.x; a1 += v0.y + v1.y; a2 += v0.z + v1.z; a3 += v0.w + v1.w;
  }
  if (j < e) {
    int r0 = psrc[j];
    float4 v0 = *(const float4*)(battr + (size_t)r0 * 256 + c);
    a0 += v0.x; a1 += v0.y; a2 += v0.z; a3 += v0.w;
  }
  *(float4*)(out + (size_t)t * 256 + c) = make_float4(a0, a1, a2, a3);
}

// ---------------- BN scale/shift + ReLU (final output only) ----------------
__global__ void k_bnrelu(const float* __restrict__ Y, const float* __restrict__ s12,
                         const float* __restrict__ g, const float* __restrict__ cb,
                         float* __restrict__ out, int ldo) {
  int i = blockIdx.x * 256 + threadIdx.x;
  int c = (i & 63) * 4;
  size_t row = (size_t)(i >> 6);
  const float invN = 1.f / (float)NCELL;
  float4 v = *(const float4*)(Y + row * 256 + c);
  float vv[4] = {v.x, v.y, v.z, v.w};
  float o[4];
#pragma unroll
  for (int k = 0; k < 4; k++) {
    float mean = s12[c + k] * invN;
    float var  = s12[256 + c + k] * invN - mean * mean;
    float sc = g[c + k] * rsqrtf(var + 1e-5f);
    float sh = cb[c + k] - mean * sc;
    o[k] = fmaxf(vv[k] * sc + sh, 0.f);
  }
  *(float4*)(out + row * (size_t)ldo + c) = make_float4(o[0], o[1], o[2], o[3]);
}

// ---------------- concat g2/c2 triples into 768-wide arrays ----------------
struct CCArgs { const float* g[3]; const float* c[3]; float* Gg; float* Gc; };
__global__ void k_concat(CCArgs a) {
  int t = blockIdx.x, i = threadIdx.x;
  a.Gg[t * 256 + i] = a.g[t][i];
  a.Gc[t * 256 + i] = a.c[t][i];
}

// ---------------- bf16 MFMA GEMM ----------------
// MODE 0: dense A (stride 256); C = acc + bias; optional fused col stats (sum,sumsq)
// MODE 1: edge-order streaming A; C[row] = relu(acc + XT[srcIdx[row]] + bias), streaming store
// MODE 2: dense A split in 3 NM-chunks (K=768); stats like MODE 0
// FUSEBN: apply y = relu(g*(x-mean)*rsqrt(var+eps)+c) per column during A staging
// Block mapping: sibling n-halves of one m-tile placed 8 ids apart -> same XCD -> A L2-reuse.
template <int MODE, int FUSEBN>
__global__ __launch_bounds__(256)
void k_gemm(const float* __restrict__ A, const uint16_t* __restrict__ Bt, int K,
            const float* __restrict__ bias, float* __restrict__ C,
            float* __restrict__ stats, float* __restrict__ statsq,
            const float* __restrict__ bnS, const float* __restrict__ bnG,
            const float* __restrict__ bnC, const int* __restrict__ srcIdx,
            const float* __restrict__ XT, int M, int gx) {
  __shared__ uint16_t Al[128 * 32];
  __shared__ uint16_t Bl[128 * 32];
  const int tid = threadIdx.x;
  int id = blockIdx.x;
  int body2 = (gx & ~7) * 2;
  int m0, n0;
  if (id < body2) {
    int g = id >> 4, j = id & 15;
    m0 = ((g << 3) + (j & 7)) * 128;
    n0 = (j >> 3) * 128;
  } else {
    int r = id - body2, rem = gx & 7;
    m0 = ((gx & ~7) + (r % rem)) * 128;
    n0 = (r / rem) * 128;
  }
  const int lane = tid & 63;
  const int wave = tid >> 6;
  const int wr = (wave >> 1) * 64;
  const int wc = (wave & 1) * 64;
  const int lm = lane & 15;
  const int lq = lane >> 4;

  f32x4 acc[4][4];
#pragma unroll
  for (int i = 0; i < 4; i++)
#pragma unroll
    for (int j = 0; j < 4; j++)
      acc[i][j] = f32x4{0.f, 0.f, 0.f, 0.f};

  const int arow = tid >> 3;        // 0..31
  const int acol = (tid & 7) * 4;   // 0,4,..,28

  int pidx[4];
#pragma unroll
  for (int rr = 0; rr < 4; rr++) {
    int gr = m0 + arow + rr * 32;
    pidx[rr] = (gr < M) ? gr : -1;
  }

  const float invN = 1.f / (float)NCELL;
  for (int kt = 0; kt < K; kt += 32) {
    float sc[4], sh[4];
    if (FUSEBN) {
#pragma unroll
      for (int k2 = 0; k2 < 4; k2++) {
        int col = kt + acol + k2;
        float mean = bnS[col] * invN;
        float var  = bnS[K + col] * invN - mean * mean;
        float s = bnG[col] * rsqrtf(var + 1e-5f);
        sc[k2] = s; sh[k2] = bnC[col] - mean * s;
      }
    }
    // stage A (fp32 -> bf16), 128 x 32
#pragma unroll
    for (int rr = 0; rr < 4; rr++) {
      int r = arow + rr * 32;
      float4 v = make_float4(0.f, 0.f, 0.f, 0.f);
      if (pidx[rr] >= 0) {
        const float* ap;
        if (MODE == 2) {
          int ct = kt + acol;
          ap = A + (size_t)(ct >> 8) * NM + (size_t)pidx[rr] * 256 + (ct & 255);
        } else {
          ap = A + (size_t)pidx[rr] * 256 + kt + acol;
        }
        v = *(const float4*)ap;
      }
      if (FUSEBN) {
        v.x = fmaxf(v.x * sc[0] + sh[0], 0.f);
        v.y = fmaxf(v.y * sc[1] + sh[1], 0.f);
        v.z = fmaxf(v.z * sc[2] + sh[2], 0.f);
        v.w = fmaxf(v.w * sc[3] + sh[3], 0.f);
      }
      union { uint16_t h[4]; uint2 u; } p;
      p.h[0] = f2bf(v.x); p.h[1] = f2bf(v.y); p.h[2] = f2bf(v.z); p.h[3] = f2bf(v.w);
      *(uint2*)(Al + r * 32 + acol) = p.u;
    }
    // stage B (bf16 B^T layout [n][k]) : tile 128 x 32
#pragma unroll
    for (int ss = 0; ss < 2; ss++) {
      int j = tid + ss * 256;
      int row = j >> 2, kp = (j & 3) * 8;
      uint4 bv = *(const uint4*)(Bt + (size_t)(n0 + row) * K + kt + kp);
      *(uint4*)(Bl + row * 32 + kp) = bv;
    }
    __syncthreads();
    bf16x8 af[4], bfr[4];
#pragma unroll
    for (int i = 0; i < 4; i++)
      af[i] = *(const bf16x8*)(Al + (wr + 16 * i + lm) * 32 + lq * 8);
#pragma unroll
    for (int j = 0; j < 4; j++)
      bfr[j] = *(const bf16x8*)(Bl + (wc + 16 * j + lm) * 32 + lq * 8);
#pragma unroll
    for (int i = 0; i < 4; i++)
#pragma unroll
      for (int j = 0; j < 4; j++)
        acc[i][j] = __builtin_amdgcn_mfma_f32_16x16x32_bf16(af[i], bfr[j], acc[i][j], 0, 0, 0);
    __syncthreads();
  }

  const int cb0 = n0 + wc + lm;
  float bj[4];
#pragma unroll
  for (int j = 0; j < 4; j++) bj[j] = bias ? bias[cb0 + 16 * j] : 0.f;

  if (MODE == 1) {
#pragma unroll
    for (int i = 0; i < 4; i++) {
      int rbase = m0 + wr + 16 * i + lq * 4;
#pragma unroll
      for (int r = 0; r < 4; r++) {
        int row = rbase + r;
        if (row < M) {
          int sr = srcIdx[row];
          const float* xr = XT + (size_t)sr * 256;
#pragma unroll
          for (int j = 0; j < 4; j++) {
            float v = acc[i][j][r] + xr[cb0 + 16 * j] + bj[j];
            C[(size_t)row * 256 + cb0 + 16 * j] = fmaxf(v, 0.f);
          }
        }
      }
    }
  } else {
    float s1l[4] = {0.f, 0.f, 0.f, 0.f}, s2l[4] = {0.f, 0.f, 0.f, 0.f};
#pragma unroll
    for (int i = 0; i < 4; i++) {
      int rbase = m0 + wr + 16 * i + lq * 4;
#pragma unroll
      for (int r = 0; r < 4; r++) {
        int row = rbase + r;
        if (row < M) {
#pragma unroll
          for (int j = 0; j < 4; j++) {
            float v = acc[i][j][r] + bj[j];
            C[(size_t)row * 256 + cb0 + 16 * j] = v;
            s1l[j] += v;
            s2l[j] += v * v;
          }
        }
      }
    }
    if (stats) {
      float* sb0 = (float*)Al;          // reuse LDS (k-loop is done)
      float* sb1 = sb0 + 128;
      __syncthreads();
      sb0[tid] = 0.f;                   // tid in [0,256): zeros sb0[0..127] and sb1[0..127]
      __syncthreads();
#pragma unroll
      for (int j = 0; j < 4; j++) {
        int colloc = wc + lm + 16 * j;
        atomicAdd(&sb0[colloc], s1l[j]);
        atomicAdd(&sb1[colloc], s2l[j]);
      }
      __syncthreads();
      if (tid < 128) {
        atomicAdd(&stats[n0 + tid],  sb0[tid]);
        atomicAdd(&statsq[n0 + tid], sb1[tid]);
      }
    }
  }
}

// ---------------- launch ----------------
extern "C" void kernel_launch(void* const* d_in, const int* in_sizes, int n_in,
                              void* d_out, int out_size, void* d_ws, size_t ws_size,
                              hipStream_t stream) {
  const float* x    = (const float*)d_in[0];
  const float* upA  = (const float*)d_in[1];
  const float* dnA  = (const float*)d_in[2];
  const float* bA   = (const float*)d_in[3];
  const float* Wmu  = (const float*)d_in[4];
  const float* bmu  = (const float*)d_in[5];
  const float* Wmd  = (const float*)d_in[6];
  const float* bmd  = (const float*)d_in[7];
  const float* W1[3] = {(const float*)d_in[8],  (const float*)d_in[16], (const float*)d_in[24]};
  const float* b1[3] = {(const float*)d_in[9],  (const float*)d_in[17], (const float*)d_in[25]};
  const float* g1[3] = {(const float*)d_in[10], (const float*)d_in[18], (const float*)d_in[26]};
  const float* c1[3] = {(const float*)d_in[11], (const float*)d_in[19], (const float*)d_in[27]};
  const float* W2[3] = {(const float*)d_in[12], (const float*)d_in[20], (const float*)d_in[28]};
  const float* b2[3] = {(const float*)d_in[13], (const float*)d_in[21], (const float*)d_in[29]};
  const float* g2[3] = {(const float*)d_in[14], (const float*)d_in[22], (const float*)d_in[30]};
  const float* c2[3] = {(const float*)d_in[15], (const float*)d_in[23], (const float*)d_in[31]};
  const float* Wc   = (const float*)d_in[32];
  const float* bc   = (const float*)d_in[33];
  const float* gc   = (const float*)d_in[34];
  const float* cc   = (const float*)d_in[35];
  const float* e1   = (const float*)d_in[36];
  const float* e2   = (const float*)d_in[37];
  const float* e3   = (const float*)d_in[38];
  const int* upI = (const int*)d_in[39];
  const int* dnI = (const int*)d_in[40];
  const int* bI  = (const int*)d_in[41];

  // ---------- workspace layout (floats) ----------
  float* base = (float*)d_ws;
  size_t o = 0;
  float* XU   = base + o; o += NM;                  // 10.24M
  float* XD   = base + o; o += NM;
  float* ACC0 = base + o; o += NM;
  float* ACC1 = base + o; o += NM;
  float* ACC2 = base + o; o += NM;
  float* POOL = base + o; o += 5 * NM;              // 51.2M floats
  float* MSG  = POOL;                               // edge phase (full 5*NM)
  float* Y3   = POOL;                               // 3*NM: raw branch outputs (pre-BN2)
  float* Y1   = POOL + 3 * NM;                      // 1*NM: pre-BN1 intermediate
  float* Yf   = POOL + 4 * NM;                      // 1*NM: final GEMM output (pre-BNc)
  float* STATS = base + o; o += 3584;               // S1 x3 (512 ea) | SCAT 1536 | SC 512
  float* SCAT = STATS + 1536;                       // [768 sums][768 sumsq]
  float* SC   = STATS + 3072;                       // [256 sums][256 sumsq]
  float* GCg  = base + o; o += 768;                 // concat g2u|g2d|g2b
  float* GCc  = base + o; o += 768;
  uint16_t* wb = (uint16_t*)(base + o); o += 600000; // bf16 weights
  uint16_t* WmuAt = wb;
  uint16_t* WmuBt = wb + 1 * 65536;
  uint16_t* WmdAt = wb + 2 * 65536;
  uint16_t* WmdBt = wb + 3 * 65536;
  uint16_t* W1t[3] = {wb + 4 * 65536, wb + 5 * 65536, wb + 6 * 65536};
  uint16_t* W2t[3] = {wb + 7 * 65536, wb + 8 * 65536, wb + 9 * 65536};
  uint16_t* Wct    = wb + 10 * 65536;               // 256 x 768
  int* ib = (int*)(base + o);
  int* offsU = ib;                 // 40001
  int* offsD = ib + 40001;
  int* offsB = ib + 80002;
  int* headU = ib + 120003;        // 40000 each (also the count array)
  int* headD = ib + 160003;
  int* headB = ib + 200003;
  int* permU = ib + 240003;        // 200000
  int* psrcU = ib + 440003;        // 200000
  int* permD = ib + 640003;
  int* psrcD = ib + 840003;
  int* permB = ib + 1040003;       // 120000
  int* psrcB = ib + 1160003;       // 120000

  float* ACCs[3] = {ACC0, ACC1, ACC2};

  hipMemsetAsync(STATS, 0, 3584 * sizeof(float), stream);
  hipMemsetAsync(headU, 0, 3 * 40000 * sizeof(int), stream);  // headU/D/B contiguous

  // weights -> bf16 B^T
  WArgs wa;
  wa.src[0] = Wmu;               wa.dst[0] = WmuAt;  wa.K[0] = 256;
  wa.src[1] = Wmu + 256 * 256;   wa.dst[1] = WmuBt;  wa.K[1] = 256;
  wa.src[2] = Wmd;               wa.dst[2] = WmdAt;  wa.K[2] = 256;
  wa.src[3] = Wmd + 256 * 256;   wa.dst[3] = WmdBt;  wa.K[3] = 256;
  for (int t = 0; t < 3; t++) {
    wa.src[4 + 2 * t] = W1[t];   wa.dst[4 + 2 * t] = W1t[t]; wa.K[4 + 2 * t] = 256;
    wa.src[5 + 2 * t] = W2[t];   wa.dst[5 + 2 * t] = W2t[t]; wa.K[5 + 2 * t] = 256;
  }
  wa.src[10] = Wc; wa.dst[10] = Wct; wa.K[10] = 768;
  k_wconv<<<dim3(24, 8, 11), dim3(32, 8), 0, stream>>>(wa);

  // g2/c2 concat for the final fused-BN GEMM
  CCArgs ca;
  for (int t = 0; t < 3; t++) { ca.g[t] = g2[t]; ca.c[t] = c2[t]; }
  ca.Gg = GCg; ca.Gc = GCc;
  k_concat<<<3, 256, 0, stream>>>(ca);

  // CSR build (targets are index[1] == ptr + E)
  k_count<<<(EUE + 255) / 256, 256, 0, stream>>>(upI + EUE, headU, EUE);
  k_count<<<(EDE + 255) / 256, 256, 0, stream>>>(dnI + EDE, headD, EDE);
  k_count<<<(EBE + 255) / 256, 256, 0, stream>>>(bI + EBE, headB, EBE);
  ScanArgs sa;
  sa.cnt[0] = headU; sa.offs[0] = offsU; sa.head[0] = headU;
  sa.cnt[1] = headD; sa.offs[1] = offsD; sa.head[1] = headD;
  sa.cnt[2] = headB; sa.offs[2] = offsB; sa.head[2] = headB;
  k_scan<<<3, 1024, 0, stream>>>(sa);
  k_fill<<<(EUE + 255) / 256, 256, 0, stream>>>(upI, upI + EUE, headU, permU, psrcU, EUE);
  k_fill<<<(EDE + 255) / 256, 256, 0, stream>>>(dnI, dnI + EDE, headD, permD, psrcD, EDE);
  k_fill<<<(EBE + 255) / 256, 256, 0, stream>>>(bI, bI + EBE, headB, permB, psrcB, EBE);

  const int gxN = (NCELL + 127) / 128;   // 313
  const int gxE = (EUE + 127) / 128;     // 1563

  // XU = x @ Wmu[:256],  XD = x @ Wmd[:256]
  k_gemm<0, 0><<<gxN * 2, 256, 0, stream>>>(x, WmuAt, 256, nullptr, XU,
      nullptr, nullptr, nullptr, nullptr, nullptr, nullptr, nullptr, NCELL, gxN);
  k_gemm<0, 0><<<gxN * 2, 256, 0, stream>>>(x, WmdAt, 256, nullptr, XD,
      nullptr, nullptr, nullptr, nullptr, nullptr, nullptr, nullptr, NCELL, gxN);

  // edge up: stream upA (edge order), relu(acc + XU[src] + bmu) -> MSG, gather-segsum -> ACC0
  k_gemm<1, 0><<<gxE * 2, 256, 0, stream>>>(upA, WmuBt, 256, bmu, MSG,
      nullptr, nullptr, nullptr, nullptr, nullptr, upI, XU, EUE, gxE);
  k_segsum<<<10000, dim3(64, 4), 0, stream>>>(MSG, offsU, permU, x, e1, ACC0);

  // edge down
  k_gemm<1, 0><<<gxE * 2, 256, 0, stream>>>(dnA, WmdBt, 256, bmd, MSG,
      nullptr, nullptr, nullptr, nullptr, nullptr, dnI, XD, EDE, gxE);
  k_segsum<<<10000, dim3(64, 4), 0, stream>>>(MSG, offsD, permD, x, e2, ACC1);

  // boundary: gather (identity messages) -> ACC2
  k_bgather<<<10000, dim3(64, 4), 0, stream>>>(bA, offsB, psrcB, x, e3, ACC2);

  // three MLP branches: GEMM1 (stats S1) -> GEMM2 (BN1 fused in A-staging, stats into SCAT)
  for (int t = 0; t < 3; t++) {
    float* S1 = STATS + 512 * t;
    k_gemm<0, 0><<<gxN * 2, 256, 0, stream>>>(ACCs[t], W1t[t], 256, b1[t], Y1,
        S1, S1 + 256, nullptr, nullptr, nullptr, nullptr, nullptr, NCELL, gxN);
    k_gemm<0, 1><<<gxN * 2, 256, 0, stream>>>(Y1, W2t[t], 256, b2[t], Y3 + t * NM,
        SCAT + t * 256, SCAT + 768 + t * 256, S1, g1[t], c1[t], nullptr, nullptr, NCELL, gxN);
  }

  // final combine: BN2(relu) fused into A-staging of CAT GEMM (K=768, 3-chunk A)
  k_gemm<2, 1><<<gxN * 2, 256, 0, stream>>>(Y3, Wct, 768, bc, Yf,
      SC, SC + 256, SCAT, GCg, GCc, nullptr, nullptr, NCELL, gxN);
  k_bnrelu<<<10000, 256, 0, stream>>>(Yf, SC, gc, cc, (float*)d_out, 256);
}

// Round 2
// 1456.517 us; speedup vs baseline: 1.1111x; 1.0226x over previous
//
#include <hip/hip_runtime.h>
#include <stdint.h>

#define NCELL 40000
#define EUE   200000
#define EDE   200000
#define EBE   120000
#define NM    ((size_t)NCELL * 256)

typedef __attribute__((ext_vector_type(8))) short bf16x8;
typedef __attribute__((ext_vector_type(4))) float f32x4;

__device__ __forceinline__ uint16_t f2bf(float f) {
  union { float f; uint32_t u; } v; v.f = f;
  uint32_t u = v.u;
  u += 0x7fffu + ((u >> 16) & 1u);   // round-to-nearest-even
  return (uint16_t)(u >> 16);
}
__device__ __forceinline__ float bf2f(uint16_t h) {
  union { uint32_t u; float f; } v; v.u = (uint32_t)h << 16; return v.f;
}
__device__ __forceinline__ uint16_t f2h(float f) {
  _Float16 h = (_Float16)f;
  union { _Float16 h; uint16_t u; } v; v.h = h; return v.u;
}
__device__ __forceinline__ float h2f(uint16_t u) {
  union { _Float16 h; uint16_t u; } v; v.u = u; return (float)v.h;
}

// async global -> LDS, 16B per lane; lds ptr must be wave-uniform base (+lane*16 by HW)
__device__ __forceinline__ void gll16(const void* g, void* l) {
  __builtin_amdgcn_global_load_lds(
      (const __attribute__((address_space(1))) uint32_t*)g,
      (__attribute__((address_space(3))) uint32_t*)l, 16, 0, 0);
}

// ---------------- weight transpose + fp32->bf16 convert ----------------
struct WArgs {
  const float* src[11];
  uint16_t*    dst[11];
  int          K[11];
};

__global__ void k_wconv(WArgs a) {
  int m = blockIdx.z;
  int K = a.K[m];
  int k0 = blockIdx.x * 32;
  if (k0 >= K) return;
  int n0 = blockIdx.y * 32;
  __shared__ float t[32][33];
  int tx = threadIdx.x, ty = threadIdx.y;
  const float* src = a.src[m];
  for (int i = ty; i < 32; i += 8)
    t[i][tx] = src[(size_t)(k0 + i) * 256 + n0 + tx];
  __syncthreads();
  uint16_t* dst = a.dst[m];
  for (int i = ty; i < 32; i += 8)
    dst[(size_t)(n0 + i) * K + k0 + tx] = f2bf(t[tx][i]);
}

// ---------------- CSR build: count -> scan -> fill ----------------
__global__ void k_count(const int* __restrict__ tgt, int* __restrict__ cnt, int E) {
  int i = blockIdx.x * 256 + threadIdx.x;
  if (i < E) atomicAdd(&cnt[tgt[i]], 1);
}

struct ScanArgs { const int* cnt[3]; int* offs[3]; int* head[3]; };

__global__ void k_scan(ScanArgs a) {
  int s = blockIdx.x;
  const int n = NCELL;
  const int* cnt = a.cnt[s];
  int* offs = a.offs[s];
  int* head = a.head[s];
  __shared__ int buf[1024];
  __shared__ int carry;
  int tid = threadIdx.x;
  if (tid == 0) carry = 0;
  __syncthreads();
  for (int base = 0; base < n; base += 1024) {
    int i = base + tid;
    int v = (i < n) ? cnt[i] : 0;
    buf[tid] = v;
    __syncthreads();
    for (int d = 1; d < 1024; d <<= 1) {
      int t = (tid >= d) ? buf[tid - d] : 0;
      __syncthreads();
      buf[tid] += t;
      __syncthreads();
    }
    int excl = carry + buf[tid] - v;
    if (i < n) { offs[i] = excl; head[i] = excl; }
    __syncthreads();
    if (tid == 1023) carry += buf[1023];
    __syncthreads();
  }
  if (tid == 0) offs[n] = carry;
}

__global__ void k_fill(const int* __restrict__ src, const int* __restrict__ tgt,
                       int* __restrict__ head, int* __restrict__ perm,
                       int* __restrict__ psrc, int E) {
  int e = blockIdx.x * 256 + threadIdx.x;
  if (e < E) {
    int p = atomicAdd(&head[tgt[e]], 1);
    perm[p] = e;
    psrc[p] = src[e];
  }
}

// ---------------- segment sum, z-batched: MSG fp16 (edge order) -> ACC bf16 ----------------
struct SSArgs {
  const uint16_t* msg[2]; const int* offs[2]; const int* perm[2];
  const float* eps[2]; uint16_t* out[2]; const float* x;
};

__global__ void k_segsum2(SSArgs a) {
  int z = blockIdx.y;
  int t = blockIdx.x * 4 + threadIdx.y;
  int c = threadIdx.x * 4;
  const int* offs = a.offs[z];
  const int* perm = a.perm[z];
  const uint16_t* MSG = a.msg[z];
  int s = offs[t], e = offs[t + 1];
  float sE = 1.f + *a.eps[z];
  float4 xa = *(const float4*)(a.x + (size_t)t * 256 + c);
  float a0 = xa.x * sE, a1 = xa.y * sE, a2 = xa.z * sE, a3 = xa.w * sE;
  int j = s;
  for (; j + 1 < e; j += 2) {
    int r0 = perm[j], r1 = perm[j + 1];
    uint2 v0 = *(const uint2*)(MSG + (size_t)r0 * 256 + c);
    uint2 v1 = *(const uint2*)(MSG + (size_t)r1 * 256 + c);
    a0 += h2f((uint16_t)v0.x) + h2f((uint16_t)v1.x);
    a1 += h2f((uint16_t)(v0.x >> 16)) + h2f((uint16_t)(v1.x >> 16));
    a2 += h2f((uint16_t)v0.y) + h2f((uint16_t)v1.y);
    a3 += h2f((uint16_t)(v0.y >> 16)) + h2f((uint16_t)(v1.y >> 16));
  }
  if (j < e) {
    int r0 = perm[j];
    uint2 v0 = *(const uint2*)(MSG + (size_t)r0 * 256 + c);
    a0 += h2f((uint16_t)v0.x);
    a1 += h2f((uint16_t)(v0.x >> 16));
    a2 += h2f((uint16_t)v0.y);
    a3 += h2f((uint16_t)(v0.y >> 16));
  }
  uint2 ov;
  ov.x = (uint32_t)f2bf(a0) | ((uint32_t)f2bf(a1) << 16);
  ov.y = (uint32_t)f2bf(a2) | ((uint32_t)f2bf(a3) << 16);
  *(uint2*)(a.out[z] + (size_t)t * 256 + c) = ov;
}

// ---------------- boundary gather: out bf16 = (1+eps)*x + sum battr[psrc[j]] ----------------
__global__ void k_bgather(const float* __restrict__ battr, const int* __restrict__ offs,
                          const int* __restrict__ psrc, const float* __restrict__ x,
                          const float* __restrict__ eps, uint16_t* __restrict__ out) {
  int t = blockIdx.x * 4 + threadIdx.y;
  int c = threadIdx.x * 4;
  int s = offs[t], e = offs[t + 1];
  float sE = 1.f + *eps;
  float4 xa = *(const float4*)(x + (size_t)t * 256 + c);
  float a0 = xa.x * sE, a1 = xa.y * sE, a2 = xa.z * sE, a3 = xa.w * sE;
  int j = s;
  for (; j + 1 < e; j += 2) {
    int r0 = psrc[j], r1 = psrc[j + 1];
    float4 v0 = *(const float4*)(battr + (size_t)r0 * 256 + c);
    float4 v1 = *(const float4*)(battr + (size_t)r1 * 256 + c);
    a0 += v0.x + v1.x; a1 += v0.y + v1.y; a2 += v0.z + v1.z; a3 += v0.w + v1.w;
  }
  if (j < e) {
    int r0 = psrc[j];
    float4 v0 = *(const float4*)(battr + (size_t)r0 * 256 + c);
    a0 += v0.x; a1 += v0.y; a2 += v0.z; a3 += v0.w;
  }
  uint2 ov;
  ov.x = (uint32_t)f2bf(a0) | ((uint32_t)f2bf(a1) << 16);
  ov.y = (uint32_t)f2bf(a2) | ((uint32_t)f2bf(a3) << 16);
  *(uint2*)(out + (size_t)t * 256 + c) = ov;
}

// ---------------- BN scale/shift precompute: sc/sh per column ----------------
struct BPArgs {
  const float* st[3]; const float* sq[3];
  const float* g[3];  const float* c[3];
  float* sc; float* sh;
};

__global__ void k_bnprep(BPArgs a) {
  int z = blockIdx.x, i = threadIdx.x;
  const float invN = 1.f / (float)NCELL;
  float mean = a.st[z][i] * invN;
  float var  = a.sq[z][i] * invN - mean * mean;
  float s = a.g[z][i] * rsqrtf(var + 1e-5f);
  a.sc[z * 256 + i] = s;
  a.sh[z * 256 + i] = a.c[z][i] - mean * s;
}

// ---------------- BN scale/shift + ReLU (final output only) ----------------
__global__ void k_bnrelu(const float* __restrict__ Y, const float* __restrict__ s12,
                         const float* __restrict__ g, const float* __restrict__ cb,
                         float* __restrict__ out, int ldo) {
  int i = blockIdx.x * 256 + threadIdx.x;
  int c = (i & 63) * 4;
  size_t row = (size_t)(i >> 6);
  const float invN = 1.f / (float)NCELL;
  float4 v = *(const float4*)(Y + row * 256 + c);
  float vv[4] = {v.x, v.y, v.z, v.w};
  float o[4];
#pragma unroll
  for (int k = 0; k < 4; k++) {
    float mean = s12[c + k] * invN;
    float var  = s12[256 + c + k] * invN - mean * mean;
    float sc = g[c + k] * rsqrtf(var + 1e-5f);
    float sh = cb[c + k] - mean * sc;
    o[k] = fmaxf(vv[k] * sc + sh, 0.f);
  }
  *(float4*)(out + row * (size_t)ldo + c) = make_float4(o[0], o[1], o[2], o[3]);
}

// ---------------- bf16 MFMA GEMM, 2-phase double-buffered pipeline ----------------
// MODE 0: dense A; MODE 1: edge-order A + fused relu(acc + XT[src] + bias) -> fp16 C
// MODE 2: A split in 3 chunks of 256 cols (K=768)
// AF32:   A is fp32 (reg-staged + convert); else A is half (GLL raw copy or FUSEBN reg path)
// FUSEBN: y = relu(a * sc[col] + sh[col]) applied in A staging (A fp16, precomputed sc/sh)
// CF32:   fp32 C (final GEMM); else fp16 C
struct GArgs {
  const void* A[3];
  const uint16_t* B[3];
  const float* bias[3];
  void* C[3];
  float* st[3]; float* stq[3];
  const float* sc[3]; const float* sh[3];
  const int* srcIdx[3];
  const uint16_t* XT[3];
  int M, K, gx;
};

template <int MODE, int AF32, int FUSEBN, int CF32>
__global__ __launch_bounds__(256)
void k_gemm(GArgs a) {
  __shared__ uint16_t Al[2][128 * 32];
  __shared__ uint16_t Bl[2][128 * 32];
  const int z = blockIdx.z;
  const int tid = threadIdx.x;
  const int gx = a.gx;
  int id = blockIdx.x;
  int body2 = (gx & ~7) * 2;
  int m0, n0;
  if (id < body2) {
    int g = id >> 4, j = id & 15;
    m0 = ((g << 3) + (j & 7)) * 128;
    n0 = (j >> 3) * 128;
  } else {
    int r = id - body2, rem = gx & 7;
    m0 = ((gx & ~7) + (r % rem)) * 128;
    n0 = (r / rem) * 128;
  }
  const int lane = tid & 63, wave = tid >> 6;
  const int wr = (wave >> 1) * 64, wc = (wave & 1) * 64;
  const int lm = lane & 15, lq = lane >> 4;
  const int M = a.M, K = a.K;
  const uint16_t* Bt = a.B[z];

  f32x4 acc[4][4];
#pragma unroll
  for (int i = 0; i < 4; i++)
#pragma unroll
    for (int j = 0; j < 4; j++)
      acc[i][j] = f32x4{0.f, 0.f, 0.f, 0.f};

  const int arow = tid >> 3;        // fp32 path: 0..31
  const int acol = (tid & 7) * 4;
  const int srow = tid >> 2;        // slot path: rows srow, srow+64
  const int sc8  = (tid & 3) * 8;

  const float* Af = (const float*)a.A[z];
  const uint16_t* Ah = (const uint16_t*)a.A[z];
  const uint16_t* A3_0 = (const uint16_t*)a.A[0];
  const uint16_t* A3_1 = (const uint16_t*)a.A[1];
  const uint16_t* A3_2 = (const uint16_t*)a.A[2];
  const float* scp = a.sc[z];
  const float* shp = a.sh[z];

  f32x4 av[4];
  uint4 ah[2];
  f32x4 scv[2][2], shv[2][2];

  auto issueB = [&](int b, int ktc) {
#pragma unroll
    for (int ss = 0; ss < 2; ss++) {
      int row = srow + ss * 64;
      gll16(Bt + (size_t)(n0 + row) * K + ktc + sc8,
            (uint16_t*)Bl[b] + (size_t)(wave * 64 + ss * 256) * 8);
    }
  };
  auto issueAg = [&](int b, int ktc) {   // GLL raw copy (A bf16, MODE 0)
#pragma unroll
    for (int ss = 0; ss < 2; ss++) {
      int row = srow + ss * 64;
      gll16(Ah + (size_t)(m0 + row) * 256 + ktc + sc8,
            (uint16_t*)Al[b] + (size_t)(wave * 64 + ss * 256) * 8);
    }
  };
  auto issueA32 = [&](int ktc) {         // fp32 A -> regs
#pragma unroll
    for (int rr = 0; rr < 4; rr++) {
      int gr = m0 + arow + rr * 32;
      av[rr] = f32x4{0.f, 0.f, 0.f, 0.f};
      if (gr < M) av[rr] = *(const f32x4*)(Af + (size_t)gr * 256 + ktc + acol);
    }
  };
  auto writeA32 = [&](int b) {           // convert + ds_write
#pragma unroll
    for (int rr = 0; rr < 4; rr++) {
      uint32_t lo = (uint32_t)f2bf(av[rr][0]) | ((uint32_t)f2bf(av[rr][1]) << 16);
      uint32_t hi = (uint32_t)f2bf(av[rr][2]) | ((uint32_t)f2bf(av[rr][3]) << 16);
      uint2 p; p.x = lo; p.y = hi;
      *(uint2*)&Al[b][(arow + rr * 32) * 32 + acol] = p;
    }
  };
  auto issueAF = [&](int ktc) {          // fp16 A + sc/sh -> regs
#pragma unroll
    for (int ss = 0; ss < 2; ss++) {
      int row = srow + ss * 64;
      int ct = ktc + sc8;
      const uint16_t* src;
      if (MODE == 2) {
        int ch = ktc >> 8;
        const uint16_t* sel = (ch == 0) ? A3_0 : (ch == 1 ? A3_1 : A3_2);
        src = sel + (size_t)(m0 + row) * 256 + (ct & 255);
      } else {
        src = Ah + (size_t)(m0 + row) * 256 + ct;
      }
      ah[ss] = *(const uint4*)src;
      scv[ss][0] = *(const f32x4*)(scp + ct);
      scv[ss][1] = *(const f32x4*)(scp + ct + 4);
      shv[ss][0] = *(const f32x4*)(shp + ct);
      shv[ss][1] = *(const f32x4*)(shp + ct + 4);
    }
  };
  auto proc2 = [&](uint32_t w, float s0, float h0, float s1, float h1) -> uint32_t {
    float v0 = fmaxf(h2f((uint16_t)w) * s0 + h0, 0.f);
    float v1 = fmaxf(h2f((uint16_t)(w >> 16)) * s1 + h1, 0.f);
    return (uint32_t)f2bf(v0) | ((uint32_t)f2bf(v1) << 16);
  };
  auto writeAF = [&](int b) {
#pragma unroll
    for (int ss = 0; ss < 2; ss++) {
      int row = srow + ss * 64;
      uint4 o;
      o.x = proc2(ah[ss].x, scv[ss][0][0], shv[ss][0][0], scv[ss][0][1], shv[ss][0][1]);
      o.y = proc2(ah[ss].y, scv[ss][0][2], shv[ss][0][2], scv[ss][0][3], shv[ss][0][3]);
      o.z = proc2(ah[ss].z, scv[ss][1][0], shv[ss][1][0], scv[ss][1][1], shv[ss][1][1]);
      o.w = proc2(ah[ss].w, scv[ss][1][2], shv[ss][1][2], scv[ss][1][3], shv[ss][1][3]);
      *(uint4*)&Al[b][row * 32 + sc8] = o;
    }
  };

  const int NT = K >> 5;
  // prologue: stage tile 0 -> buf 0
  issueB(0, 0);
  if constexpr (AF32)        { issueA32(0); writeA32(0); }
  else if constexpr (FUSEBN) { issueAF(0);  writeAF(0);  }
  else                       issueAg(0, 0);
  __syncthreads();

  int cur = 0;
  for (int T = 0; T < NT; T++) {
    bool more = (T + 1 < NT);
    int nk = (T + 1) << 5;
    if (more) {
      issueB(cur ^ 1, nk);
      if constexpr (AF32)        issueA32(nk);
      else if constexpr (FUSEBN) issueAF(nk);
      else                       issueAg(cur ^ 1, nk);
    }
    bf16x8 af[4], bfr[4];
#pragma unroll
    for (int i = 0; i < 4; i++)
      af[i] = *(const bf16x8*)&Al[cur][(wr + 16 * i + lm) * 32 + lq * 8];
#pragma unroll
    for (int j = 0; j < 4; j++)
      bfr[j] = *(const bf16x8*)&Bl[cur][(wc + 16 * j + lm) * 32 + lq * 8];
#pragma unroll
    for (int i = 0; i < 4; i++)
#pragma unroll
      for (int j = 0; j < 4; j++)
        acc[i][j] = __builtin_amdgcn_mfma_f32_16x16x32_bf16(af[i], bfr[j], acc[i][j], 0, 0, 0);
    if (more) {
      if constexpr (AF32)        writeA32(cur ^ 1);
      else if constexpr (FUSEBN) writeAF(cur ^ 1);
    }
    __syncthreads();
    cur ^= 1;
  }

  const int cb0 = n0 + wc + lm;
  const float* bias = a.bias[z];
  float bj[4];
#pragma unroll
  for (int j = 0; j < 4; j++) bj[j] = bias ? bias[cb0 + 16 * j] : 0.f;

  if constexpr (MODE == 1) {
    const int* sidx = a.srcIdx[z];
    const uint16_t* XTz = a.XT[z];
    uint16_t* Cz = (uint16_t*)a.C[z];
#pragma unroll
    for (int i = 0; i < 4; i++) {
      int rbase = m0 + wr + 16 * i + lq * 4;
#pragma unroll
      for (int r = 0; r < 4; r++) {
        int row = rbase + r;
        if (row < M) {
          int sr = sidx[row];
          const uint16_t* xr = XTz + (size_t)sr * 256;
#pragma unroll
          for (int j = 0; j < 4; j++) {
            float v = acc[i][j][r] + h2f(xr[cb0 + 16 * j]) + bj[j];
            Cz[(size_t)row * 256 + cb0 + 16 * j] = f2h(fmaxf(v, 0.f));
          }
        }
      }
    }
  } else {
    float s1l[4] = {0.f, 0.f, 0.f, 0.f}, s2l[4] = {0.f, 0.f, 0.f, 0.f};
    float* Cf = (float*)a.C[z];
    uint16_t* Ch = (uint16_t*)a.C[z];
#pragma unroll
    for (int i = 0; i < 4; i++) {
      int rbase = m0 + wr + 16 * i + lq * 4;
#pragma unroll
      for (int r = 0; r < 4; r++) {
        int row = rbase + r;
        if (row < M) {
#pragma unroll
          for (int j = 0; j < 4; j++) {
            float v = acc[i][j][r] + bj[j];
            if constexpr (CF32) Cf[(size_t)row * 256 + cb0 + 16 * j] = v;
            else                Ch[(size_t)row * 256 + cb0 + 16 * j] = f2h(v);
            s1l[j] += v;
            s2l[j] += v * v;
          }
        }
      }
    }
    if (a.st[z]) {
      float* sb0 = (float*)Al;          // reuse LDS
      float* sb1 = sb0 + 128;
      __syncthreads();
      sb0[tid] = 0.f;                   // zeros sb0[0..127] and sb1[0..127]
      __syncthreads();
#pragma unroll
      for (int j = 0; j < 4; j++) {
        int colloc = wc + lm + 16 * j;
        atomicAdd(&sb0[colloc], s1l[j]);
        atomicAdd(&sb1[colloc], s2l[j]);
      }
      __syncthreads();
      if (tid < 128) {
        atomicAdd(&a.st[z][n0 + tid],  sb0[tid]);
        atomicAdd(&a.stq[z][n0 + tid], sb1[tid]);
      }
    }
  }
}

// ---------------- launch ----------------
extern "C" void kernel_launch(void* const* d_in, const int* in_sizes, int n_in,
                              void* d_out, int out_size, void* d_ws, size_t ws_size,
                              hipStream_t stream) {
  const float* x    = (const float*)d_in[0];
  const float* upA  = (const float*)d_in[1];
  const float* dnA  = (const float*)d_in[2];
  const float* bA   = (const float*)d_in[3];
  const float* Wmu  = (const float*)d_in[4];
  const float* bmu  = (const float*)d_in[5];
  const float* Wmd  = (const float*)d_in[6];
  const float* bmd  = (const float*)d_in[7];
  const float* W1[3] = {(const float*)d_in[8],  (const float*)d_in[16], (const float*)d_in[24]};
  const float* b1[3] = {(const float*)d_in[9],  (const float*)d_in[17], (const float*)d_in[25]};
  const float* g1[3] = {(const float*)d_in[10], (const float*)d_in[18], (const float*)d_in[26]};
  const float* c1[3] = {(const float*)d_in[11], (const float*)d_in[19], (const float*)d_in[27]};
  const float* W2[3] = {(const float*)d_in[12], (const float*)d_in[20], (const float*)d_in[28]};
  const float* b2[3] = {(const float*)d_in[13], (const float*)d_in[21], (const float*)d_in[29]};
  const float* g2[3] = {(const float*)d_in[14], (const float*)d_in[22], (const float*)d_in[30]};
  const float* c2[3] = {(const float*)d_in[15], (const float*)d_in[23], (const float*)d_in[31]};
  const float* Wc   = (const float*)d_in[32];
  const float* bc   = (const float*)d_in[33];
  const float* gc   = (const float*)d_in[34];
  const float* cc   = (const float*)d_in[35];
  const float* e1   = (const float*)d_in[36];
  const float* e2   = (const float*)d_in[37];
  const float* e3   = (const float*)d_in[38];
  const int* upI = (const int*)d_in[39];
  const int* dnI = (const int*)d_in[40];
  const int* bI  = (const int*)d_in[41];

  // ---------- workspace layout (float units) ----------
  float* base = (float*)d_ws;
  size_t o = 0;
  uint16_t* XUb = (uint16_t*)(base + o); o += NM / 2;       // fp16, NM elems
  uint16_t* XDb = (uint16_t*)(base + o); o += NM / 2;
  uint16_t* ACCb[3];
  for (int t = 0; t < 3; t++) { ACCb[t] = (uint16_t*)(base + o); o += NM / 2; }  // bf16
  float* POOL = base + o; o += 5 * NM;
  uint16_t* MSGb[2] = {(uint16_t*)POOL, (uint16_t*)(POOL + 5 * NM / 2)};  // fp16, EUE*256 each
  uint16_t* Y1b = (uint16_t*)POOL;                          // fp16, 3 x NM elems
  uint16_t* Y3b = (uint16_t*)(POOL + 3 * NM / 2);           // fp16, 3 x NM elems
  float* Yf = POOL + 3 * NM;                                // fp32, NM
  float* STATS = base + o; o += 3584;    // S1 x3 (512 ea) | SCAT 1536 | SC 512
  float* SCAT = STATS + 1536;
  float* SCp  = STATS + 3072;
  float* SCSH1 = base + o; o += 1536;    // sc 768 | sh 768
  float* SCSH2 = base + o; o += 1536;
  uint16_t* wb = (uint16_t*)(base + o); o += 600000;        // bf16 weights
  uint16_t* WmuAt = wb;
  uint16_t* WmuBt = wb + 1 * 65536;
  uint16_t* WmdAt = wb + 2 * 65536;
  uint16_t* WmdBt = wb + 3 * 65536;
  uint16_t* W1t[3] = {wb + 4 * 65536, wb + 5 * 65536, wb + 6 * 65536};
  uint16_t* W2t[3] = {wb + 7 * 65536, wb + 8 * 65536, wb + 9 * 65536};
  uint16_t* Wct    = wb + 10 * 65536;                       // 256 x 768
  int* ib = (int*)(base + o);
  int* offsU = ib;
  int* offsD = ib + 40001;
  int* offsB = ib + 80002;
  int* headU = ib + 120003;
  int* headD = ib + 160003;
  int* headB = ib + 200003;
  int* permU = ib + 240003;
  int* psrcU = ib + 440003;
  int* permD = ib + 640003;
  int* psrcD = ib + 840003;
  int* permB = ib + 1040003;
  int* psrcB = ib + 1160003;

  hipMemsetAsync(STATS, 0, 3584 * sizeof(float), stream);
  hipMemsetAsync(headU, 0, 3 * 40000 * sizeof(int), stream);

  // weights -> bf16 B^T
  WArgs wa;
  wa.src[0] = Wmu;               wa.dst[0] = WmuAt;  wa.K[0] = 256;
  wa.src[1] = Wmu + 256 * 256;   wa.dst[1] = WmuBt;  wa.K[1] = 256;
  wa.src[2] = Wmd;               wa.dst[2] = WmdAt;  wa.K[2] = 256;
  wa.src[3] = Wmd + 256 * 256;   wa.dst[3] = WmdBt;  wa.K[3] = 256;
  for (int t = 0; t < 3; t++) {
    wa.src[4 + 2 * t] = W1[t];   wa.dst[4 + 2 * t] = W1t[t]; wa.K[4 + 2 * t] = 256;
    wa.src[5 + 2 * t] = W2[t];   wa.dst[5 + 2 * t] = W2t[t]; wa.K[5 + 2 * t] = 256;
  }
  wa.src[10] = Wc; wa.dst[10] = Wct; wa.K[10] = 768;
  k_wconv<<<dim3(24, 8, 11), dim3(32, 8), 0, stream>>>(wa);

  // CSR build (targets = index[1] == ptr + E); perm for segsum, psrc for boundary
  k_count<<<(EUE + 255) / 256, 256, 0, stream>>>(upI + EUE, headU, EUE);
  k_count<<<(EDE + 255) / 256, 256, 0, stream>>>(dnI + EDE, headD, EDE);
  k_count<<<(EBE + 255) / 256, 256, 0, stream>>>(bI + EBE, headB, EBE);
  ScanArgs sa;
  sa.cnt[0] = headU; sa.offs[0] = offsU; sa.head[0] = headU;
  sa.cnt[1] = headD; sa.offs[1] = offsD; sa.head[1] = headD;
  sa.cnt[2] = headB; sa.offs[2] = offsB; sa.head[2] = headB;
  k_scan<<<3, 1024, 0, stream>>>(sa);
  k_fill<<<(EUE + 255) / 256, 256, 0, stream>>>(upI, upI + EUE, headU, permU, psrcU, EUE);
  k_fill<<<(EDE + 255) / 256, 256, 0, stream>>>(dnI, dnI + EDE, headD, permD, psrcD, EDE);
  k_fill<<<(EBE + 255) / 256, 256, 0, stream>>>(bI, bI + EBE, headB, permB, psrcB, EBE);

  const int gxN = (NCELL + 127) / 128;   // 313
  const int gxE = (EUE + 127) / 128;     // 1563

  // XU = x @ Wmu[:256], XD = x @ Wmd[:256]  (z-batched, fp16 out)
  {
    GArgs g{};
    g.A[0] = x; g.A[1] = x;
    g.B[0] = WmuAt; g.B[1] = WmdAt;
    g.C[0] = XUb; g.C[1] = XDb;
    g.M = NCELL; g.K = 256; g.gx = gxN;
    k_gemm<0, 1, 0, 0><<<dim3(gxN * 2, 1, 2), 256, 0, stream>>>(g);
  }

  // edges (z-batched): MSG[e] = relu(attr[e] @ WB + XT[src[e]] + b)  -> fp16, edge order
  {
    GArgs g{};
    g.A[0] = upA; g.A[1] = dnA;
    g.B[0] = WmuBt; g.B[1] = WmdBt;
    g.bias[0] = bmu; g.bias[1] = bmd;
    g.C[0] = MSGb[0]; g.C[1] = MSGb[1];
    g.srcIdx[0] = upI; g.srcIdx[1] = dnI;
    g.XT[0] = XUb; g.XT[1] = XDb;
    g.M = EUE; g.K = 256; g.gx = gxE;
    k_gemm<1, 1, 0, 0><<<dim3(gxE * 2, 1, 2), 256, 0, stream>>>(g);
  }

  // segment sums (z-batched) -> ACC0/ACC1 bf16
  {
    SSArgs s{};
    s.msg[0] = MSGb[0]; s.msg[1] = MSGb[1];
    s.offs[0] = offsU;  s.offs[1] = offsD;
    s.perm[0] = permU;  s.perm[1] = permD;
    s.eps[0] = e1;      s.eps[1] = e2;
    s.out[0] = ACCb[0]; s.out[1] = ACCb[1];
    s.x = x;
    k_segsum2<<<dim3(10000, 2), dim3(64, 4), 0, stream>>>(s);
  }

  // boundary -> ACC2 bf16
  k_bgather<<<10000, dim3(64, 4), 0, stream>>>(bA, offsB, psrcB, x, e3, ACCb[2]);

  // branch GEMM1 (z=3, GLL bf16 A): Y1 fp16 + S1 stats
  {
    GArgs g{};
    for (int t = 0; t < 3; t++) {
      g.A[t] = ACCb[t];
      g.B[t] = W1t[t];
      g.bias[t] = b1[t];
      g.C[t] = Y1b + (size_t)t * NM;
      g.st[t] = STATS + 512 * t; g.stq[t] = STATS + 512 * t + 256;
    }
    g.M = NCELL; g.K = 256; g.gx = gxN;
    k_gemm<0, 0, 0, 0><<<dim3(gxN * 2, 1, 3), 256, 0, stream>>>(g);
  }

  // BN1 scale/shift precompute
  {
    BPArgs b{};
    for (int t = 0; t < 3; t++) {
      b.st[t] = STATS + 512 * t; b.sq[t] = STATS + 512 * t + 256;
      b.g[t] = g1[t]; b.c[t] = c1[t];
    }
    b.sc = SCSH1; b.sh = SCSH1 + 768;
    k_bnprep<<<3, 256, 0, stream>>>(b);
  }

  // branch GEMM2 (z=3, FUSEBN on Y1): Y3 fp16 + SCAT stats
  {
    GArgs g{};
    for (int t = 0; t < 3; t++) {
      g.A[t] = Y1b + (size_t)t * NM;
      g.B[t] = W2t[t];
      g.bias[t] = b2[t];
      g.C[t] = Y3b + (size_t)t * NM;
      g.st[t] = SCAT + 256 * t; g.stq[t] = SCAT + 768 + 256 * t;
      g.sc[t] = SCSH1 + 256 * t; g.sh[t] = SCSH1 + 768 + 256 * t;
    }
    g.M = NCELL; g.K = 256; g.gx = gxN;
    k_gemm<0, 0, 1, 0><<<dim3(gxN * 2, 1, 3), 256, 0, stream>>>(g);
  }

  // BN2 scale/shift precompute (768 flat)
  {
    BPArgs b{};
    for (int t = 0; t < 3; t++) {
      b.st[t] = SCAT + 256 * t; b.sq[t] = SCAT + 768 + 256 * t;
      b.g[t] = g2[t]; b.c[t] = c2[t];
    }
    b.sc = SCSH2; b.sh = SCSH2 + 768;
    k_bnprep<<<3, 256, 0, stream>>>(b);
  }

  // final combine: BN2(relu) fused into A staging; K=768 over 3 chunks; Yf fp32 + SC stats
  {
    GArgs g{};
    g.A[0] = Y3b; g.A[1] = Y3b + NM; g.A[2] = Y3b + 2 * NM;
    g.B[0] = Wct;
    g.bias[0] = bc;
    g.C[0] = Yf;
    g.st[0] = SCp; g.stq[0] = SCp + 256;
    g.sc[0] = SCSH2; g.sh[0] = SCSH2 + 768;
    g.M = NCELL; g.K = 768; g.gx = gxN;
    k_gemm<2, 0, 1, 1><<<dim3(gxN * 2, 1, 1), 256, 0, stream>>>(g);
  }

  k_bnrelu<<<10000, 256, 0, stream>>>(Yf, SCp, gc, cc, (float*)d_out, 256);
}